// Round 10
// baseline (438.677 us; speedup 1.0000x reference)
//
#include <hip/hip_runtime.h>
#include <hip/hip_cooperative_groups.h>
#include <math.h>

namespace cg = cooperative_groups;

#define DIV_UP(a,b) (((a)+(b)-1)/(b))

typedef __attribute__((ext_vector_type(8))) short bf16x8;
typedef __attribute__((ext_vector_type(4))) float f32x4;

// fp32 -> bf16 round-to-nearest-even
__device__ inline unsigned short f2b(float x) {
    unsigned int u = __float_as_uint(x);
    u += 0x7fffu + ((u >> 16) & 1u);
    return (unsigned short)(u >> 16);
}

// 8 packed bf16 (uint4) -> 8 floats
__device__ inline void cvt8(uint4 v, float* a) {
    a[0] = __uint_as_float(v.x << 16); a[1] = __uint_as_float(v.x & 0xffff0000u);
    a[2] = __uint_as_float(v.y << 16); a[3] = __uint_as_float(v.y & 0xffff0000u);
    a[4] = __uint_as_float(v.z << 16); a[5] = __uint_as_float(v.z & 0xffff0000u);
    a[6] = __uint_as_float(v.w << 16); a[7] = __uint_as_float(v.w & 0xffff0000u);
}

// async global->LDS 16B
__device__ inline void gl16(void* lds, const void* g) {
    __builtin_amdgcn_global_load_lds(
        (const __attribute__((address_space(1))) void*)g,
        (__attribute__((address_space(3))) void*)lds, 16, 0, 0);
}

// ============ cooperative build kernel ============
// 256 blocks x 1024 threads. Phases separated by grid.sync():
//  P0: zero hist/cursor; x->bf16; W1^T; W2^T; Wc collapse; graph bounds
//  P1: degree histogram (int atomics)
//  P2: per-block chunk sums -> bsum[256]
//  P3: LDS scan of bsum (redundant per block) + chunk prefix -> row_off, dinv
//  P4: bin edges into dst-CSR
__global__ __launch_bounds__(1024) void k_build(
        const int* __restrict__ src, const int* __restrict__ dst, int E,
        int* __restrict__ hist, int* __restrict__ cursor, int* __restrict__ bsum,
        int* __restrict__ row_off, float* __restrict__ dinv, int N,
        int* __restrict__ csr_src, float* __restrict__ csr_w,
        const int* __restrict__ batch, int* __restrict__ bounds, int G,
        const float* __restrict__ W3, const float* __restrict__ W4,
        const float* __restrict__ W5, const float* __restrict__ b3,
        const float* __restrict__ b4, const float* __restrict__ b5,
        float* __restrict__ WcT, float* __restrict__ bc,
        const float* __restrict__ x, unsigned short* __restrict__ xb, int n4,
        const float* __restrict__ W1, unsigned short* __restrict__ w1t, int K1, int N1,
        const float* __restrict__ W2, unsigned short* __restrict__ w2t, int K2, int N2) {
    cg::grid_group grid = cg::this_grid();
    __shared__ float shf[256];
    __shared__ int ssc[1024];
    const int nb = gridDim.x;
    const int b = blockIdx.x, t = threadIdx.x;
    const int gtid = b * blockDim.x + t;
    const int gsz = nb * blockDim.x;

    // ---- P0 ----
    for (int i = gtid; i < N; i += gsz) { hist[i] = 0; cursor[i] = 0; }
    for (int i = gtid; i < n4; i += gsz) {
        float4 v = ((const float4*)x)[i];
        ushort4 o;
        o.x = f2b(v.x); o.y = f2b(v.y); o.z = f2b(v.z); o.w = f2b(v.w);
        ((ushort4*)xb)[i] = o;
    }
    for (int i = gtid; i < K1 * N1; i += gsz) {
        int k = i / N1, n = i % N1;
        w1t[(size_t)n * K1 + k] = f2b(W1[i]);
    }
    for (int i = gtid; i < K2 * N2; i += gsz) {
        int k = i / N2, n = i % N2;
        w2t[(size_t)n * K2 + k] = f2b(W2[i]);
    }
    for (int g = gtid; g <= G; g += gsz) {
        int lo = 0, hi = N;
        while (lo < hi) { int mid = (lo + hi) >> 1; if (batch[mid] < g) lo = mid + 1; else hi = mid; }
        bounds[g] = lo;
    }
    if (b < 10) {                     // WcT row c = b
        int c = b;
        if (t < 128) {
            float s = 0.f;
#pragma unroll 8
            for (int k = 0; k < 32; ++k) s = fmaf(W4[t * 32 + k], W5[k * 10 + c], s);
            shf[t] = s;
        }
        __syncthreads();
        if (t < 256) {
            float s = 0.f;
            const float* w3r = &W3[t * 128];
#pragma unroll 8
            for (int j = 0; j < 128; ++j) s = fmaf(w3r[j], shf[j], s);
            WcT[c * 256 + t] = s;
        }
        __syncthreads();
    } else if (b == 10) {             // bias chain
        if (t < 32) {
            float s = b4[t];
            for (int j = 0; j < 128; ++j) s = fmaf(b3[j], W4[j * 32 + t], s);
            shf[t] = s;
        }
        __syncthreads();
        if (t < 10) {
            float s = b5[t];
            for (int k = 0; k < 32; ++k) s = fmaf(shf[k], W5[k * 10 + t], s);
            bc[t] = s;
        }
        __syncthreads();
    }
    grid.sync();

    // ---- P1: histogram ----
    for (int i = gtid; i < E; i += gsz) atomicAdd(&hist[dst[i]], 1);
    grid.sync();

    // ---- P2: chunk sums ----
    const int chunk = DIV_UP(N, nb);
    const int beg = b * chunk;
    const int end = min(beg + chunk, N);
    {
        int s = 0;
        for (int i = beg + t; i < end; i += 1024) s += hist[i];
        ssc[t] = s;
        __syncthreads();
        for (int off = 512; off >= 1; off >>= 1) {
            if (t < off) ssc[t] += ssc[t + off];
            __syncthreads();
        }
        if (t == 0) bsum[b] = ssc[0];
    }
    grid.sync();

    // ---- P3: scan bsum in LDS (all blocks redundantly) + chunk prefix ----
    {
        int v = (t < nb) ? bsum[t] : 0;
        ssc[t] = v;
        __syncthreads();
        for (int off = 1; off < 1024; off <<= 1) {
            int u = (t >= off) ? ssc[t - off] : 0;
            __syncthreads();
            ssc[t] += u;
            __syncthreads();
        }
        int boffv = (b == 0) ? 0 : ssc[b - 1];
        __syncthreads();
        int carry = boffv;
        for (int s0 = beg; s0 < end; s0 += 1024) {
            int i = s0 + t;
            int v2 = (i < end) ? hist[i] : 0;
            ssc[t] = v2;
            __syncthreads();
            for (int off = 1; off < 1024; off <<= 1) {
                int u = (t >= off) ? ssc[t - off] : 0;
                __syncthreads();
                ssc[t] += u;
                __syncthreads();
            }
            if (i < end) {
                row_off[i] = carry + ssc[t] - v2;
                dinv[i] = rsqrtf((float)(v2 + 1));
            }
            carry += ssc[1023];
            __syncthreads();
        }
        if (b == nb - 1 && t == 0) row_off[N] = carry;
    }
    grid.sync();

    // ---- P4: bin edges ----
    for (int i = gtid; i < E; i += gsz) {
        int d = dst[i], s = src[i];
        int pos = row_off[d] + atomicAdd(&cursor[d], 1);
        csr_src[pos] = s;
        csr_w[pos] = dinv[s] * dinv[d];
    }
}

// gather-aggregate over dst-CSR, bf16 in/out, ILP-8 edge loop.
template <int F>
__global__ __launch_bounds__(256) void k_gather_b(const unsigned short* __restrict__ H,
        const int* __restrict__ row_off, const int* __restrict__ csr_src,
        const float* __restrict__ csr_w, const float* __restrict__ dinv,
        const float* __restrict__ bias, unsigned short* __restrict__ outb, int N) {
    const int LPN = F / 8;
    const int NPB = 256 / LPN;
    int node = blockIdx.x * NPB + threadIdx.x / LPN;
    if (node >= N) return;
    int f = (threadIdx.x % LPN) * 8;
    const unsigned short* Hf = H + f;
    float sc = dinv[node]; sc *= sc;
    float a[8];
    cvt8(*(const uint4*)&Hf[(size_t)node * F], a);
#pragma unroll
    for (int j = 0; j < 8; ++j) a[j] *= sc;
    if (bias) {
#pragma unroll
        for (int j = 0; j < 8; ++j) a[j] += bias[f + j];
    }
    int e0 = row_off[node], e1 = row_off[node + 1];
    int e = e0;
    // 8 independent row fetches in flight
    for (; e + 8 <= e1; e += 8) {
        int ss[8];
        uint4 vv[8];
        float ww[8];
#pragma unroll
        for (int q = 0; q < 8; ++q) ss[q] = csr_src[e + q];
#pragma unroll
        for (int q = 0; q < 8; ++q) vv[q] = *(const uint4*)&Hf[(size_t)ss[q] * F];
#pragma unroll
        for (int q = 0; q < 8; ++q) ww[q] = csr_w[e + q];
#pragma unroll
        for (int q = 0; q < 8; ++q) {
            float bb[8];
            cvt8(vv[q], bb);
#pragma unroll
            for (int j = 0; j < 8; ++j) a[j] = fmaf(ww[q], bb[j], a[j]);
        }
    }
    for (; e + 4 <= e1; e += 4) {
        int s0 = csr_src[e + 0], s1 = csr_src[e + 1];
        int s2 = csr_src[e + 2], s3 = csr_src[e + 3];
        uint4 v0 = *(const uint4*)&Hf[(size_t)s0 * F];
        uint4 v1 = *(const uint4*)&Hf[(size_t)s1 * F];
        uint4 v2 = *(const uint4*)&Hf[(size_t)s2 * F];
        uint4 v3 = *(const uint4*)&Hf[(size_t)s3 * F];
        float w0 = csr_w[e + 0], w1 = csr_w[e + 1];
        float w2 = csr_w[e + 2], w3 = csr_w[e + 3];
        float b0[8], b1[8], b2[8], b3[8];
        cvt8(v0, b0); cvt8(v1, b1); cvt8(v2, b2); cvt8(v3, b3);
#pragma unroll
        for (int j = 0; j < 8; ++j) {
            a[j] = fmaf(w0, b0[j], a[j]);
            a[j] = fmaf(w1, b1[j], a[j]);
            a[j] = fmaf(w2, b2[j], a[j]);
            a[j] = fmaf(w3, b3[j], a[j]);
        }
    }
    for (; e < e1; ++e) {
        int s = csr_src[e];
        float w = csr_w[e];
        float b[8];
        cvt8(*(const uint4*)&Hf[(size_t)s * F], b);
#pragma unroll
        for (int j = 0; j < 8; ++j) a[j] = fmaf(w, b[j], a[j]);
    }
    uint4 o;
    o.x = (unsigned)f2b(a[0]) | ((unsigned)f2b(a[1]) << 16);
    o.y = (unsigned)f2b(a[2]) | ((unsigned)f2b(a[3]) << 16);
    o.z = (unsigned)f2b(a[4]) | ((unsigned)f2b(a[5]) << 16);
    o.w = (unsigned)f2b(a[6]) | ((unsigned)f2b(a[7]) << 16);
    *(uint4*)&outb[(size_t)node * F + f] = o;
}

// bf16 MFMA GEMM, fat-N tile: 128x256 per block, 512 threads = 8 waves (2x4),
// each wave 64x64 via 4x4 grid of 16x16x32 MFMAs, BK=64, global_load_lds w16,
// XOR-swizzled LDS, operand-swap mfma (lane = row + 4 contiguous cols).
template <int OUT_BF16, int ACT>
__global__ __launch_bounds__(512) void k_gemm_mfma256(const unsigned short* __restrict__ A,
        const unsigned short* __restrict__ Bt, const float* __restrict__ bias,
        void* __restrict__ Cout, int M, int K, int NC) {
    __shared__ __align__(16) unsigned short As[128][64];
    __shared__ __align__(16) unsigned short Bs[256][64];
    int tid = threadIdx.x;
    int wave = tid >> 6, lane = tid & 63;
    int row0 = blockIdx.y * 128, col0 = blockIdx.x * 256;
    int wr = (wave >> 2) * 64, wc = (wave & 3) * 64;
    f32x4 acc[4][4] = {};
    int lr = lane & 15;
    int lg = lane >> 4;
    int sw = ((lane & 7) ^ (lane >> 3)) << 3;
    int ch0 = (lg ^ (lr & 7)) << 3;
    int ch1 = ch0 ^ (4 << 3);

    for (int k0 = 0; k0 < K; k0 += 64) {
#pragma unroll
        for (int c = 0; c < 2; ++c) {
            int rl = c * 64 + wave * 8 + (lane >> 3);
            int gr = min(row0 + rl, M - 1);
            gl16(&As[c * 64 + wave * 8][0], &A[(size_t)gr * K + k0 + sw]);
        }
#pragma unroll
        for (int c = 0; c < 4; ++c) {
            int rl = c * 64 + wave * 8 + (lane >> 3);
            gl16(&Bs[c * 64 + wave * 8][0], &Bt[(size_t)(col0 + rl) * K + k0 + sw]);
        }
        __syncthreads();
        bf16x8 af[2][4], bv[2][4];
#pragma unroll
        for (int i = 0; i < 4; ++i) {
            int ra = wr + i * 16 + lr;
            int rb = wc + i * 16 + lr;
            af[0][i] = *(const bf16x8*)&As[ra][ch0];
            af[1][i] = *(const bf16x8*)&As[ra][ch1];
            bv[0][i] = *(const bf16x8*)&Bs[rb][ch0];
            bv[1][i] = *(const bf16x8*)&Bs[rb][ch1];
        }
#pragma unroll
        for (int s = 0; s < 2; ++s)
#pragma unroll
            for (int i = 0; i < 4; ++i)
#pragma unroll
                for (int j = 0; j < 4; ++j)
                    acc[i][j] = __builtin_amdgcn_mfma_f32_16x16x32_bf16(bv[s][j], af[s][i], acc[i][j], 0, 0, 0);
        __syncthreads();
    }

    int q4 = lg * 4;
    float4 bb[4];
#pragma unroll
    for (int j = 0; j < 4; ++j)
        bb[j] = bias ? *(const float4*)&bias[col0 + wc + j * 16 + q4]
                     : make_float4(0.f, 0.f, 0.f, 0.f);
#pragma unroll
    for (int i = 0; i < 4; ++i) {
        int row = row0 + wr + i * 16 + lr;
        if (row >= M) continue;
#pragma unroll
        for (int j = 0; j < 4; ++j) {
            int c0 = col0 + wc + j * 16 + q4;
            float4 v;
            v.x = acc[i][j][0] + bb[j].x;
            v.y = acc[i][j][1] + bb[j].y;
            v.z = acc[i][j][2] + bb[j].z;
            v.w = acc[i][j][3] + bb[j].w;
            if (ACT) {
                v.x = (v.x >= 0.f) ? v.x : 0.01f * v.x;
                v.y = (v.y >= 0.f) ? v.y : 0.01f * v.y;
                v.z = (v.z >= 0.f) ? v.z : 0.01f * v.z;
                v.w = (v.w >= 0.f) ? v.w : 0.01f * v.w;
            }
            if (OUT_BF16) {
                uint2 o;
                o.x = (unsigned)f2b(v.x) | ((unsigned)f2b(v.y) << 16);
                o.y = (unsigned)f2b(v.z) | ((unsigned)f2b(v.w) << 16);
                *(uint2*)&((unsigned short*)Cout)[(size_t)row * NC + c0] = o;
            } else {
                *(float4*)&((float*)Cout)[(size_t)row * NC + c0] = v;
            }
        }
    }
}

// fused per-graph output: phase A = head (h2 @ Wc + bc, max over rows -> out[g,:10]);
// phase B = feature-wise segment_max of h2 -> out_emb[g,:256].
__global__ __launch_bounds__(320) void k_head_segmax(const unsigned short* __restrict__ H,
        const float* __restrict__ WcT, const float* __restrict__ bc,
        const int* __restrict__ bounds, float* __restrict__ out,
        float* __restrict__ out_emb) {
    __shared__ __align__(16) float Ws[10][260];
    __shared__ float bs[10];
    __shared__ float red[320];
    int t = threadIdx.x;
    for (int i = t; i < 2560; i += 320) Ws[i / 256][i % 256] = WcT[i];
    if (t < 10) bs[t] = bc[t];
    __syncthreads();
    int g = blockIdx.x;
    int s = bounds[g], e = bounds[g + 1];
    int col = t % 10, rs = t / 10;
    float m = -INFINITY;
    for (int r = s + rs; r < e; r += 32) {
        const unsigned short* hr = &H[(size_t)r * 256];
        float acc = bs[col];
#pragma unroll 4
        for (int k = 0; k < 256; k += 8) {
            float h[8];
            cvt8(*(const uint4*)&hr[k], h);
            float4 wa = *(const float4*)&Ws[col][k];
            float4 wb = *(const float4*)&Ws[col][k + 4];
            acc = fmaf(h[0], wa.x, acc);
            acc = fmaf(h[1], wa.y, acc);
            acc = fmaf(h[2], wa.z, acc);
            acc = fmaf(h[3], wa.w, acc);
            acc = fmaf(h[4], wb.x, acc);
            acc = fmaf(h[5], wb.y, acc);
            acc = fmaf(h[6], wb.z, acc);
            acc = fmaf(h[7], wb.w, acc);
        }
        m = fmaxf(m, acc);
    }
    red[t] = m;
    __syncthreads();
    for (int step = 16; step >= 1; step >>= 1) {
        if (rs < step) red[rs * 10 + col] = fmaxf(red[rs * 10 + col], red[(rs + step) * 10 + col]);
        __syncthreads();
    }
    if (rs == 0) out[(size_t)g * 10 + col] = red[col];
    if (t < 256) {
        float mm = -INFINITY;
        for (int r = s; r < e; ++r)
            mm = fmaxf(mm, __uint_as_float(((unsigned)H[(size_t)r * 256 + t]) << 16));
        out_emb[(size_t)g * 256 + t] = mm;
    }
}

extern "C" void kernel_launch(void* const* d_in, const int* in_sizes, int n_in,
                              void* d_out, int out_size, void* d_ws, size_t ws_size,
                              hipStream_t stream) {
    const float* x  = (const float*)d_in[0];
    const int* ei   = (const int*)d_in[1];
    const int* batch= (const int*)d_in[2];
    const float* W1 = (const float*)d_in[3];
    const float* b1 = (const float*)d_in[4];
    const float* W2 = (const float*)d_in[5];
    const float* b2 = (const float*)d_in[6];
    const float* W3 = (const float*)d_in[7];
    const float* b3 = (const float*)d_in[8];
    const float* W4 = (const float*)d_in[9];
    const float* b4 = (const float*)d_in[10];
    const float* W5 = (const float*)d_in[11];
    const float* b5 = (const float*)d_in[12];

    const int N  = in_sizes[2];           // 50000
    const int F  = in_sizes[0] / N;       // 128
    int E        = in_sizes[1] / 2;       // 400000
    const int C1 = in_sizes[4];           // 512
    const int C2 = in_sizes[6];           // 256
    const int C5 = in_sizes[12];          // 10
    const int G  = out_size / (C2 + C5);  // 512

    const int* srcp = ei;
    const int* dstp = ei + E;

    // ---- workspace layout (256B-aligned carve-outs) ----
    uintptr_t p = (uintptr_t)d_ws;
    auto carve = [&](size_t bytes) {
        uintptr_t r = p;
        p += (bytes + 255) & ~(size_t)255;
        return (void*)r;
    };
    int* hist    = (int*)carve(sizeof(int) * N);
    int* cursor  = (int*)carve(sizeof(int) * N);
    int* row_off = (int*)carve(sizeof(int) * (N + 1));
    int* bounds  = (int*)carve(sizeof(int) * (G + 1));
    int* bsum    = (int*)carve(sizeof(int) * 256);
    int* csr_src = (int*)carve(sizeof(int) * E);
    float* csr_w = (float*)carve(sizeof(float) * E);
    float* dinv  = (float*)carve(sizeof(float) * N);
    float* wct   = (float*)carve(sizeof(float) * C2 * C5);
    float* bcv   = (float*)carve(sizeof(float) * C5);
    unsigned short* w1t = (unsigned short*)carve(sizeof(short) * F * C1);
    unsigned short* w2t = (unsigned short*)carve(sizeof(short) * C1 * C2);
    unsigned short* xb    = (unsigned short*)carve(sizeof(short) * (size_t)N * F);
    unsigned short* aggxb = (unsigned short*)carve(sizeof(short) * (size_t)N * F);
    unsigned short* h1b   = (unsigned short*)carve(sizeof(short) * (size_t)N * C1);
    unsigned short* t2b   = (unsigned short*)carve(sizeof(short) * (size_t)N * C2);
    unsigned short* h2b   = (unsigned short*)carve(sizeof(short) * (size_t)N * C2);

    float* out     = (float*)d_out;
    float* out_emb = out + (size_t)G * C5;

    // ---- single cooperative build kernel ----
    int n4 = N * F / 4;
    int K1 = F, N1 = C1, K2 = C1, N2v = C2;
    int Nv = N, Gv = G, Ev = E;
    void* cargs[] = {
        (void*)&srcp, (void*)&dstp, (void*)&Ev,
        (void*)&hist, (void*)&cursor, (void*)&bsum,
        (void*)&row_off, (void*)&dinv, (void*)&Nv,
        (void*)&csr_src, (void*)&csr_w,
        (void*)&batch, (void*)&bounds, (void*)&Gv,
        (void*)&W3, (void*)&W4, (void*)&W5, (void*)&b3, (void*)&b4, (void*)&b5,
        (void*)&wct, (void*)&bcv,
        (void*)&x, (void*)&xb, (void*)&n4,
        (void*)&W1, (void*)&w1t, (void*)&K1, (void*)&N1,
        (void*)&W2, (void*)&w2t, (void*)&K2, (void*)&N2v };
    hipLaunchCooperativeKernel((void*)k_build, dim3(256), dim3(1024), cargs, 0, stream);

    // ---- layer 1: gather (bf16) -> fat-N MFMA GEMM + bias + leakyrelu -> h1 bf16 ----
    k_gather_b<128><<<DIV_UP(N, 16), 256, 0, stream>>>(
        xb, row_off, csr_src, csr_w, dinv, nullptr, aggxb, N);
    dim3 g1(C1 / 256, DIV_UP(N, 128));
    k_gemm_mfma256<1, 1><<<g1, 512, 0, stream>>>(aggxb, w1t, b1, h1b, N, F, C1);

    // ---- layer 2: fat-N MFMA GEMM -> t2 bf16 -> gather (+b2) -> h2 bf16 ----
    dim3 g2(C2 / 256, DIV_UP(N, 128));
    k_gemm_mfma256<1, 0><<<g2, 512, 0, stream>>>(h1b, w2t, nullptr, t2b, N, C1, C2);
    k_gather_b<256><<<DIV_UP(N, 8), 256, 0, stream>>>(
        t2b, row_off, csr_src, csr_w, dinv, b2, h2b, N);

    // ---- fused head + both segment_maxes ----
    k_head_segmax<<<G, 320, 0, stream>>>(h2b, wct, bcv, bounds, out, out_emb);
}

// Round 11
// 293.463 us; speedup vs baseline: 1.4948x; 1.4948x over previous
//
#include <hip/hip_runtime.h>
#include <math.h>

#define DIV_UP(a,b) (((a)+(b)-1)/(b))

typedef __attribute__((ext_vector_type(8))) short bf16x8;
typedef __attribute__((ext_vector_type(4))) float f32x4;

// fp32 -> bf16 round-to-nearest-even
__device__ inline unsigned short f2b(float x) {
    unsigned int u = __float_as_uint(x);
    u += 0x7fffu + ((u >> 16) & 1u);
    return (unsigned short)(u >> 16);
}

// 8 packed bf16 (uint4) -> 8 floats
__device__ inline void cvt8(uint4 v, float* a) {
    a[0] = __uint_as_float(v.x << 16); a[1] = __uint_as_float(v.x & 0xffff0000u);
    a[2] = __uint_as_float(v.y << 16); a[3] = __uint_as_float(v.y & 0xffff0000u);
    a[4] = __uint_as_float(v.z << 16); a[5] = __uint_as_float(v.z & 0xffff0000u);
    a[6] = __uint_as_float(v.w << 16); a[7] = __uint_as_float(v.w & 0xffff0000u);
}

// async global->LDS 16B
__device__ inline void gl16(void* lds, const void* g) {
    __builtin_amdgcn_global_load_lds(
        (const __attribute__((address_space(1))) void*)g,
        (__attribute__((address_space(3))) void*)lds, 16, 0, 0);
}

__global__ void k_zero_i(int* p, int n) {
    int i = blockIdx.x * blockDim.x + threadIdx.x;
    if (i < n) p[i] = 0;
}

__global__ void k_hist(const int* __restrict__ dst, int* __restrict__ hist, int E) {
    int i = blockIdx.x * blockDim.x + threadIdx.x;
    if (i < E) atomicAdd(&hist[dst[i]], 1);
}

// ---- hierarchical scan ----
__global__ __launch_bounds__(256) void k_scan_bsum(const int* __restrict__ hist,
                                                   int* __restrict__ bsum, int N) {
    __shared__ int red[256];
    int t = threadIdx.x;
    int base = blockIdx.x * 1024 + t * 4;
    int s = 0;
    if (base + 3 < N) {
        int4 v = *(const int4*)&hist[base];
        s = v.x + v.y + v.z + v.w;
    } else {
        for (int j = 0; j < 4; ++j) if (base + j < N) s += hist[base + j];
    }
    red[t] = s;
    __syncthreads();
    for (int off = 128; off >= 1; off >>= 1) {
        if (t < off) red[t] += red[t + off];
        __syncthreads();
    }
    if (t == 0) bsum[blockIdx.x] = red[0];
}

__global__ __launch_bounds__(1024) void k_scan_boff(const int* __restrict__ bsum,
        int* __restrict__ boff, int* __restrict__ row_off, int NB, int N) {
    __shared__ int s[1024];
    int t = threadIdx.x;
    int v = (t < NB) ? bsum[t] : 0;
    s[t] = v;
    __syncthreads();
    for (int off = 1; off < 1024; off <<= 1) {
        int u = (t >= off) ? s[t - off] : 0;
        __syncthreads();
        s[t] += u;
        __syncthreads();
    }
    if (t < NB) boff[t] = s[t] - v;
    if (t == NB - 1) row_off[N] = s[t];
}

// scan apply + dinv fused
__global__ __launch_bounds__(256) void k_scan_apply(const int* __restrict__ hist,
        const int* __restrict__ boff, int* __restrict__ row_off,
        float* __restrict__ dinv, int N) {
    __shared__ int s[256];
    int t = threadIdx.x;
    int base = blockIdx.x * 1024 + t * 4;
    int v[4];
    int loc = 0;
#pragma unroll
    for (int j = 0; j < 4; ++j) { v[j] = (base + j < N) ? hist[base + j] : 0; loc += v[j]; }
    s[t] = loc;
    __syncthreads();
    for (int off = 1; off < 256; off <<= 1) {
        int u = (t >= off) ? s[t - off] : 0;
        __syncthreads();
        s[t] += u;
        __syncthreads();
    }
    int run = boff[blockIdx.x] + s[t] - loc;
#pragma unroll
    for (int j = 0; j < 4; ++j) {
        if (base + j < N) {
            row_off[base + j] = run;
            dinv[base + j] = rsqrtf((float)(v[j] + 1));
        }
        run += v[j];
    }
}

__global__ void k_bin(const int* __restrict__ src, const int* __restrict__ dst,
                      const int* __restrict__ row_off, int* __restrict__ cursor,
                      const float* __restrict__ dinv,
                      int* __restrict__ csr_src, float* __restrict__ csr_w, int E) {
    int i = blockIdx.x * blockDim.x + threadIdx.x;
    if (i >= E) return;
    int d = dst[i], s = src[i];
    int pos = row_off[d] + atomicAdd(&cursor[d], 1);
    csr_src[pos] = s;
    csr_w[pos] = dinv[s] * dinv[d];
}

// fused preprocessing, block-range partitioned:
//   blocks [0,11):        head-weight collapse (WcT = (W3@W4@W5)^T, bc chain)
//   blocks [11,11+nb):    graph bounds binary search
//   blocks [11+nb, ...):  x->bf16, W1^T->bf16, W2^T->bf16
__global__ __launch_bounds__(256) void k_pre(
        const float* __restrict__ W3, const float* __restrict__ W4,
        const float* __restrict__ W5, const float* __restrict__ b3,
        const float* __restrict__ b4, const float* __restrict__ b5,
        float* __restrict__ WcT, float* __restrict__ bc,
        const int* __restrict__ batch, int* __restrict__ bounds, int N, int G, int nb,
        const float* __restrict__ x, unsigned short* __restrict__ xb, int n4,
        const float* __restrict__ W1, unsigned short* __restrict__ w1t, int K1, int N1,
        const float* __restrict__ W2, unsigned short* __restrict__ w2t, int K2, int N2) {
    int b = blockIdx.x;
    int t = threadIdx.x;
    if (b < 11) {
        int c = b;
        if (c < 10) {
            __shared__ float Tc[128];
            if (t < 128) {
                float s = 0.f;
#pragma unroll 8
                for (int k = 0; k < 32; ++k) s = fmaf(W4[t * 32 + k], W5[k * 10 + c], s);
                Tc[t] = s;
            }
            __syncthreads();
            float s = 0.f;
            const float* w3r = &W3[t * 128];
#pragma unroll 8
            for (int j = 0; j < 128; ++j) s = fmaf(w3r[j], Tc[j], s);
            WcT[c * 256 + t] = s;
        } else {
            __shared__ float v[32];
            if (t < 32) {
                float s = b4[t];
                for (int j = 0; j < 128; ++j) s = fmaf(b3[j], W4[j * 32 + t], s);
                v[t] = s;
            }
            __syncthreads();
            if (t < 10) {
                float s = b5[t];
                for (int k = 0; k < 32; ++k) s = fmaf(v[k], W5[k * 10 + t], s);
                bc[t] = s;
            }
        }
        return;
    }
    if (b < 11 + nb) {
        int g = (b - 11) * 256 + t;
        if (g > G) return;
        int lo = 0, hi = N;
        while (lo < hi) { int mid = (lo + hi) >> 1; if (batch[mid] < g) lo = mid + 1; else hi = mid; }
        bounds[g] = lo;
        return;
    }
    int i = (b - 11 - nb) * 256 + t;
    if (i < n4) {
        float4 v = ((const float4*)x)[i];
        ushort4 o;
        o.x = f2b(v.x); o.y = f2b(v.y); o.z = f2b(v.z); o.w = f2b(v.w);
        ((ushort4*)xb)[i] = o;
        return;
    }
    i -= n4;
    if (i < K1 * N1) {
        int k = i / N1, n = i % N1;
        w1t[(size_t)n * K1 + k] = f2b(W1[i]);
        return;
    }
    i -= K1 * N1;
    if (i < K2 * N2) {
        int k = i / N2, n = i % N2;
        w2t[(size_t)n * K2 + k] = f2b(W2[i]);
    }
}

// gather-aggregate over dst-CSR, bf16 in/out, ILP-8 edge loop.
template <int F>
__global__ __launch_bounds__(256) void k_gather_b(const unsigned short* __restrict__ H,
        const int* __restrict__ row_off, const int* __restrict__ csr_src,
        const float* __restrict__ csr_w, const float* __restrict__ dinv,
        const float* __restrict__ bias, unsigned short* __restrict__ outb, int N) {
    const int LPN = F / 8;
    const int NPB = 256 / LPN;
    int node = blockIdx.x * NPB + threadIdx.x / LPN;
    if (node >= N) return;
    int f = (threadIdx.x % LPN) * 8;
    const unsigned short* Hf = H + f;
    float sc = dinv[node]; sc *= sc;
    float a[8];
    cvt8(*(const uint4*)&Hf[(size_t)node * F], a);
#pragma unroll
    for (int j = 0; j < 8; ++j) a[j] *= sc;
    if (bias) {
#pragma unroll
        for (int j = 0; j < 8; ++j) a[j] += bias[f + j];
    }
    int e0 = row_off[node], e1 = row_off[node + 1];
    int e = e0;
    // 8 independent row fetches in flight
    for (; e + 8 <= e1; e += 8) {
        int ss[8];
        uint4 vv[8];
        float ww[8];
#pragma unroll
        for (int q = 0; q < 8; ++q) ss[q] = csr_src[e + q];
#pragma unroll
        for (int q = 0; q < 8; ++q) vv[q] = *(const uint4*)&Hf[(size_t)ss[q] * F];
#pragma unroll
        for (int q = 0; q < 8; ++q) ww[q] = csr_w[e + q];
#pragma unroll
        for (int q = 0; q < 8; ++q) {
            float bb[8];
            cvt8(vv[q], bb);
#pragma unroll
            for (int j = 0; j < 8; ++j) a[j] = fmaf(ww[q], bb[j], a[j]);
        }
    }
    for (; e + 4 <= e1; e += 4) {
        int s0 = csr_src[e + 0], s1 = csr_src[e + 1];
        int s2 = csr_src[e + 2], s3 = csr_src[e + 3];
        uint4 v0 = *(const uint4*)&Hf[(size_t)s0 * F];
        uint4 v1 = *(const uint4*)&Hf[(size_t)s1 * F];
        uint4 v2 = *(const uint4*)&Hf[(size_t)s2 * F];
        uint4 v3 = *(const uint4*)&Hf[(size_t)s3 * F];
        float w0 = csr_w[e + 0], w1 = csr_w[e + 1];
        float w2 = csr_w[e + 2], w3 = csr_w[e + 3];
        float b0[8], b1[8], b2[8], b3[8];
        cvt8(v0, b0); cvt8(v1, b1); cvt8(v2, b2); cvt8(v3, b3);
#pragma unroll
        for (int j = 0; j < 8; ++j) {
            a[j] = fmaf(w0, b0[j], a[j]);
            a[j] = fmaf(w1, b1[j], a[j]);
            a[j] = fmaf(w2, b2[j], a[j]);
            a[j] = fmaf(w3, b3[j], a[j]);
        }
    }
    for (; e < e1; ++e) {
        int s = csr_src[e];
        float w = csr_w[e];
        float b[8];
        cvt8(*(const uint4*)&Hf[(size_t)s * F], b);
#pragma unroll
        for (int j = 0; j < 8; ++j) a[j] = fmaf(w, b[j], a[j]);
    }
    uint4 o;
    o.x = (unsigned)f2b(a[0]) | ((unsigned)f2b(a[1]) << 16);
    o.y = (unsigned)f2b(a[2]) | ((unsigned)f2b(a[3]) << 16);
    o.z = (unsigned)f2b(a[4]) | ((unsigned)f2b(a[5]) << 16);
    o.w = (unsigned)f2b(a[6]) | ((unsigned)f2b(a[7]) << 16);
    *(uint4*)&outb[(size_t)node * F + f] = o;
}

// bf16 MFMA GEMM, fat-N tile: 128x256 per block, 512 threads = 8 waves (2x4),
// each wave 64x64 via 4x4 grid of 16x16x32 MFMAs, BK=64, global_load_lds w16,
// XOR-swizzled LDS, operand-swap mfma (lane = row + 4 contiguous cols).
template <int OUT_BF16, int ACT>
__global__ __launch_bounds__(512) void k_gemm_mfma256(const unsigned short* __restrict__ A,
        const unsigned short* __restrict__ Bt, const float* __restrict__ bias,
        void* __restrict__ Cout, int M, int K, int NC) {
    __shared__ __align__(16) unsigned short As[128][64];
    __shared__ __align__(16) unsigned short Bs[256][64];
    int tid = threadIdx.x;
    int wave = tid >> 6, lane = tid & 63;
    int row0 = blockIdx.y * 128, col0 = blockIdx.x * 256;
    int wr = (wave >> 2) * 64, wc = (wave & 3) * 64;
    f32x4 acc[4][4] = {};
    int lr = lane & 15;
    int lg = lane >> 4;
    int sw = ((lane & 7) ^ (lane >> 3)) << 3;
    int ch0 = (lg ^ (lr & 7)) << 3;
    int ch1 = ch0 ^ (4 << 3);

    for (int k0 = 0; k0 < K; k0 += 64) {
#pragma unroll
        for (int c = 0; c < 2; ++c) {
            int rl = c * 64 + wave * 8 + (lane >> 3);
            int gr = min(row0 + rl, M - 1);
            gl16(&As[c * 64 + wave * 8][0], &A[(size_t)gr * K + k0 + sw]);
        }
#pragma unroll
        for (int c = 0; c < 4; ++c) {
            int rl = c * 64 + wave * 8 + (lane >> 3);
            gl16(&Bs[c * 64 + wave * 8][0], &Bt[(size_t)(col0 + rl) * K + k0 + sw]);
        }
        __syncthreads();
        bf16x8 af[2][4], bv[2][4];
#pragma unroll
        for (int i = 0; i < 4; ++i) {
            int ra = wr + i * 16 + lr;
            int rb = wc + i * 16 + lr;
            af[0][i] = *(const bf16x8*)&As[ra][ch0];
            af[1][i] = *(const bf16x8*)&As[ra][ch1];
            bv[0][i] = *(const bf16x8*)&Bs[rb][ch0];
            bv[1][i] = *(const bf16x8*)&Bs[rb][ch1];
        }
#pragma unroll
        for (int s = 0; s < 2; ++s)
#pragma unroll
            for (int i = 0; i < 4; ++i)
#pragma unroll
                for (int j = 0; j < 4; ++j)
                    acc[i][j] = __builtin_amdgcn_mfma_f32_16x16x32_bf16(bv[s][j], af[s][i], acc[i][j], 0, 0, 0);
        __syncthreads();
    }

    int q4 = lg * 4;
    float4 bb[4];
#pragma unroll
    for (int j = 0; j < 4; ++j)
        bb[j] = bias ? *(const float4*)&bias[col0 + wc + j * 16 + q4]
                     : make_float4(0.f, 0.f, 0.f, 0.f);
#pragma unroll
    for (int i = 0; i < 4; ++i) {
        int row = row0 + wr + i * 16 + lr;
        if (row >= M) continue;
#pragma unroll
        for (int j = 0; j < 4; ++j) {
            int c0 = col0 + wc + j * 16 + q4;
            float4 v;
            v.x = acc[i][j][0] + bb[j].x;
            v.y = acc[i][j][1] + bb[j].y;
            v.z = acc[i][j][2] + bb[j].z;
            v.w = acc[i][j][3] + bb[j].w;
            if (ACT) {
                v.x = (v.x >= 0.f) ? v.x : 0.01f * v.x;
                v.y = (v.y >= 0.f) ? v.y : 0.01f * v.y;
                v.z = (v.z >= 0.f) ? v.z : 0.01f * v.z;
                v.w = (v.w >= 0.f) ? v.w : 0.01f * v.w;
            }
            if (OUT_BF16) {
                uint2 o;
                o.x = (unsigned)f2b(v.x) | ((unsigned)f2b(v.y) << 16);
                o.y = (unsigned)f2b(v.z) | ((unsigned)f2b(v.w) << 16);
                *(uint2*)&((unsigned short*)Cout)[(size_t)row * NC + c0] = o;
            } else {
                *(float4*)&((float*)Cout)[(size_t)row * NC + c0] = v;
            }
        }
    }
}

// fused per-graph output: phase A = head (h2 @ Wc + bc, max over rows -> out[g,:10]);
// phase B = feature-wise segment_max of h2 -> out_emb[g,:256].
__global__ __launch_bounds__(320) void k_head_segmax(const unsigned short* __restrict__ H,
        const float* __restrict__ WcT, const float* __restrict__ bc,
        const int* __restrict__ bounds, float* __restrict__ out,
        float* __restrict__ out_emb) {
    __shared__ __align__(16) float Ws[10][260];
    __shared__ float bs[10];
    __shared__ float red[320];
    int t = threadIdx.x;
    for (int i = t; i < 2560; i += 320) Ws[i / 256][i % 256] = WcT[i];
    if (t < 10) bs[t] = bc[t];
    __syncthreads();
    int g = blockIdx.x;
    int s = bounds[g], e = bounds[g + 1];
    int col = t % 10, rs = t / 10;
    float m = -INFINITY;
    for (int r = s + rs; r < e; r += 32) {
        const unsigned short* hr = &H[(size_t)r * 256];
        float acc = bs[col];
#pragma unroll 4
        for (int k = 0; k < 256; k += 8) {
            float h[8];
            cvt8(*(const uint4*)&hr[k], h);
            float4 wa = *(const float4*)&Ws[col][k];
            float4 wb = *(const float4*)&Ws[col][k + 4];
            acc = fmaf(h[0], wa.x, acc);
            acc = fmaf(h[1], wa.y, acc);
            acc = fmaf(h[2], wa.z, acc);
            acc = fmaf(h[3], wa.w, acc);
            acc = fmaf(h[4], wb.x, acc);
            acc = fmaf(h[5], wb.y, acc);
            acc = fmaf(h[6], wb.z, acc);
            acc = fmaf(h[7], wb.w, acc);
        }
        m = fmaxf(m, acc);
    }
    red[t] = m;
    __syncthreads();
    for (int step = 16; step >= 1; step >>= 1) {
        if (rs < step) red[rs * 10 + col] = fmaxf(red[rs * 10 + col], red[(rs + step) * 10 + col]);
        __syncthreads();
    }
    if (rs == 0) out[(size_t)g * 10 + col] = red[col];
    if (t < 256) {
        float mm = -INFINITY;
        for (int r = s; r < e; ++r)
            mm = fmaxf(mm, __uint_as_float(((unsigned)H[(size_t)r * 256 + t]) << 16));
        out_emb[(size_t)g * 256 + t] = mm;
    }
}

extern "C" void kernel_launch(void* const* d_in, const int* in_sizes, int n_in,
                              void* d_out, int out_size, void* d_ws, size_t ws_size,
                              hipStream_t stream) {
    const float* x  = (const float*)d_in[0];
    const int* ei   = (const int*)d_in[1];
    const int* batch= (const int*)d_in[2];
    const float* W1 = (const float*)d_in[3];
    const float* b1 = (const float*)d_in[4];
    const float* W2 = (const float*)d_in[5];
    const float* b2 = (const float*)d_in[6];
    const float* W3 = (const float*)d_in[7];
    const float* b3 = (const float*)d_in[8];
    const float* W4 = (const float*)d_in[9];
    const float* b4 = (const float*)d_in[10];
    const float* W5 = (const float*)d_in[11];
    const float* b5 = (const float*)d_in[12];

    const int N  = in_sizes[2];           // 50000
    const int F  = in_sizes[0] / N;       // 128
    const int E  = in_sizes[1] / 2;       // 400000
    const int C1 = in_sizes[4];           // 512
    const int C2 = in_sizes[6];           // 256
    const int C5 = in_sizes[12];          // 10
    const int G  = out_size / (C2 + C5);  // 512
    const int NB = DIV_UP(N, 1024);

    const int* srcp = ei;
    const int* dstp = ei + E;

    // ---- workspace layout (256B-aligned carve-outs) ----
    uintptr_t p = (uintptr_t)d_ws;
    auto carve = [&](size_t bytes) {
        uintptr_t r = p;
        p += (bytes + 255) & ~(size_t)255;
        return (void*)r;
    };
    int* hist    = (int*)carve(sizeof(int) * N);
    int* cursor  = (int*)carve(sizeof(int) * N);      // MUST follow hist (joint zero-fill)
    int* row_off = (int*)carve(sizeof(int) * (N + 1));
    int* bounds  = (int*)carve(sizeof(int) * (G + 1));
    int* bsum    = (int*)carve(sizeof(int) * NB);
    int* boff    = (int*)carve(sizeof(int) * NB);
    int* csr_src = (int*)carve(sizeof(int) * E);
    float* csr_w = (float*)carve(sizeof(float) * E);
    float* dinv  = (float*)carve(sizeof(float) * N);
    float* wct   = (float*)carve(sizeof(float) * C2 * C5);
    float* bcv   = (float*)carve(sizeof(float) * C5);
    unsigned short* w1t = (unsigned short*)carve(sizeof(short) * F * C1);
    unsigned short* w2t = (unsigned short*)carve(sizeof(short) * C1 * C2);
    unsigned short* xb    = (unsigned short*)carve(sizeof(short) * (size_t)N * F);
    unsigned short* aggxb = (unsigned short*)carve(sizeof(short) * (size_t)N * F);
    unsigned short* h1b   = (unsigned short*)carve(sizeof(short) * (size_t)N * C1);
    unsigned short* t2b   = (unsigned short*)carve(sizeof(short) * (size_t)N * C2);
    unsigned short* h2b   = (unsigned short*)carve(sizeof(short) * (size_t)N * C2);

    float* out     = (float*)d_out;
    float* out_emb = out + (size_t)G * C5;

    // ---- CSR build + fused preprocessing (multi-kernel; launches beat grid.sync) ----
    int zspan = (int)(((sizeof(int) * N + 255) & ~(size_t)255) / 4) + N;  // hist..cursor
    k_zero_i<<<DIV_UP(zspan, 256), 256, 0, stream>>>(hist, zspan);
    k_hist<<<DIV_UP(E, 256), 256, 0, stream>>>(dstp, hist, E);
    k_scan_bsum<<<NB, 256, 0, stream>>>(hist, bsum, N);
    k_scan_boff<<<1, 1024, 0, stream>>>(bsum, boff, row_off, NB, N);
    k_scan_apply<<<NB, 256, 0, stream>>>(hist, boff, row_off, dinv, N);
    k_bin<<<DIV_UP(E, 256), 256, 0, stream>>>(srcp, dstp, row_off, cursor, dinv,
                                              csr_src, csr_w, E);

    int n4 = N * F / 4;
    int nb_bounds = DIV_UP(G + 1, 256);
    int prep_total = n4 + F * C1 + C1 * C2;
    int pre_blocks = 11 + nb_bounds + DIV_UP(prep_total, 256);
    k_pre<<<pre_blocks, 256, 0, stream>>>(W3, W4, W5, b3, b4, b5, wct, bcv,
                                          batch, bounds, N, G, nb_bounds,
                                          x, xb, n4, W1, w1t, F, C1, W2, w2t, C1, C2);

    // ---- layer 1: gather (bf16) -> fat-N MFMA GEMM + bias + leakyrelu -> h1 bf16 ----
    k_gather_b<128><<<DIV_UP(N, 16), 256, 0, stream>>>(
        xb, row_off, csr_src, csr_w, dinv, nullptr, aggxb, N);
    dim3 g1(C1 / 256, DIV_UP(N, 128));
    k_gemm_mfma256<1, 1><<<g1, 512, 0, stream>>>(aggxb, w1t, b1, h1b, N, F, C1);

    // ---- layer 2: fat-N MFMA GEMM -> t2 bf16 -> gather (+b2) -> h2 bf16 ----
    dim3 g2(C2 / 256, DIV_UP(N, 128));
    k_gemm_mfma256<1, 0><<<g2, 512, 0, stream>>>(h1b, w2t, nullptr, t2b, N, C1, C2);
    k_gather_b<256><<<DIV_UP(N, 8), 256, 0, stream>>>(
        t2b, row_off, csr_src, csr_w, dinv, b2, h2b, N);

    // ---- fused head + both segment_maxes ----
    k_head_segmax<<<G, 320, 0, stream>>>(h2b, wct, bcv, bounds, out, out_emb);
}

// Round 12
// 287.204 us; speedup vs baseline: 1.5274x; 1.0218x over previous
//
#include <hip/hip_runtime.h>
#include <math.h>

#define DIV_UP(a,b) (((a)+(b)-1)/(b))

typedef __attribute__((ext_vector_type(8))) short bf16x8;
typedef __attribute__((ext_vector_type(4))) float f32x4;

// fp32 -> bf16 round-to-nearest-even
__device__ inline unsigned short f2b(float x) {
    unsigned int u = __float_as_uint(x);
    u += 0x7fffu + ((u >> 16) & 1u);
    return (unsigned short)(u >> 16);
}

// 8 packed bf16 (uint4) -> 8 floats
__device__ inline void cvt8(uint4 v, float* a) {
    a[0] = __uint_as_float(v.x << 16); a[1] = __uint_as_float(v.x & 0xffff0000u);
    a[2] = __uint_as_float(v.y << 16); a[3] = __uint_as_float(v.y & 0xffff0000u);
    a[4] = __uint_as_float(v.z << 16); a[5] = __uint_as_float(v.z & 0xffff0000u);
    a[6] = __uint_as_float(v.w << 16); a[7] = __uint_as_float(v.w & 0xffff0000u);
}

// async global->LDS 16B
__device__ inline void gl16(void* lds, const void* g) {
    __builtin_amdgcn_global_load_lds(
        (const __attribute__((address_space(1))) void*)g,
        (__attribute__((address_space(3))) void*)lds, 16, 0, 0);
}

__global__ void k_hist(const int* __restrict__ dst, int* __restrict__ hist, int E) {
    int i = blockIdx.x * blockDim.x + threadIdx.x;
    if (i < E) atomicAdd(&hist[dst[i]], 1);
}

// ---- hierarchical scan ----
__global__ __launch_bounds__(256) void k_scan_bsum(const int* __restrict__ hist,
                                                   int* __restrict__ bsum, int N) {
    __shared__ int red[256];
    int t = threadIdx.x;
    int base = blockIdx.x * 1024 + t * 4;
    int s = 0;
    if (base + 3 < N) {
        int4 v = *(const int4*)&hist[base];
        s = v.x + v.y + v.z + v.w;
    } else {
        for (int j = 0; j < 4; ++j) if (base + j < N) s += hist[base + j];
    }
    red[t] = s;
    __syncthreads();
    for (int off = 128; off >= 1; off >>= 1) {
        if (t < off) red[t] += red[t + off];
        __syncthreads();
    }
    if (t == 0) bsum[blockIdx.x] = red[0];
}

__global__ __launch_bounds__(1024) void k_scan_boff(const int* __restrict__ bsum,
        int* __restrict__ boff, int* __restrict__ row_off, int NB, int N) {
    __shared__ int s[1024];
    int t = threadIdx.x;
    int v = (t < NB) ? bsum[t] : 0;
    s[t] = v;
    __syncthreads();
    for (int off = 1; off < 1024; off <<= 1) {
        int u = (t >= off) ? s[t - off] : 0;
        __syncthreads();
        s[t] += u;
        __syncthreads();
    }
    if (t < NB) boff[t] = s[t] - v;
    if (t == NB - 1) row_off[N] = s[t];
}

// scan apply + dinv fused
__global__ __launch_bounds__(256) void k_scan_apply(const int* __restrict__ hist,
        const int* __restrict__ boff, int* __restrict__ row_off,
        float* __restrict__ dinv, int N) {
    __shared__ int s[256];
    int t = threadIdx.x;
    int base = blockIdx.x * 1024 + t * 4;
    int v[4];
    int loc = 0;
#pragma unroll
    for (int j = 0; j < 4; ++j) { v[j] = (base + j < N) ? hist[base + j] : 0; loc += v[j]; }
    s[t] = loc;
    __syncthreads();
    for (int off = 1; off < 256; off <<= 1) {
        int u = (t >= off) ? s[t - off] : 0;
        __syncthreads();
        s[t] += u;
        __syncthreads();
    }
    int run = boff[blockIdx.x] + s[t] - loc;
#pragma unroll
    for (int j = 0; j < 4; ++j) {
        if (base + j < N) {
            row_off[base + j] = run;
            dinv[base + j] = rsqrtf((float)(v[j] + 1));
        }
        run += v[j];
    }
}

// bin edges into packed CSR {src, w_bits}: one 8B scatter per edge
__global__ void k_bin(const int* __restrict__ src, const int* __restrict__ dst,
                      const int* __restrict__ row_off, int* __restrict__ cursor,
                      const float* __restrict__ dinv,
                      int2* __restrict__ csr, int E) {
    int i = blockIdx.x * blockDim.x + threadIdx.x;
    if (i >= E) return;
    int d = dst[i], s = src[i];
    int pos = row_off[d] + atomicAdd(&cursor[d], 1);
    int2 ent;
    ent.x = s;
    ent.y = __float_as_int(dinv[s] * dinv[d]);
    csr[pos] = ent;
}

// fused preprocessing, block-range partitioned:
//   blocks [0,11):        head-weight collapse (WcT = (W3@W4@W5)^T, bc chain)
//   blocks [11,11+nb):    graph bounds binary search
//   blocks [11+nb, ...):  x->bf16, W1^T->bf16, W2^T->bf16
__global__ __launch_bounds__(256) void k_pre(
        const float* __restrict__ W3, const float* __restrict__ W4,
        const float* __restrict__ W5, const float* __restrict__ b3,
        const float* __restrict__ b4, const float* __restrict__ b5,
        float* __restrict__ WcT, float* __restrict__ bc,
        const int* __restrict__ batch, int* __restrict__ bounds, int N, int G, int nb,
        const float* __restrict__ x, unsigned short* __restrict__ xb, int n4,
        const float* __restrict__ W1, unsigned short* __restrict__ w1t, int K1, int N1,
        const float* __restrict__ W2, unsigned short* __restrict__ w2t, int K2, int N2) {
    int b = blockIdx.x;
    int t = threadIdx.x;
    if (b < 11) {
        int c = b;
        if (c < 10) {
            __shared__ float Tc[128];
            if (t < 128) {
                float s = 0.f;
#pragma unroll 8
                for (int k = 0; k < 32; ++k) s = fmaf(W4[t * 32 + k], W5[k * 10 + c], s);
                Tc[t] = s;
            }
            __syncthreads();
            float s = 0.f;
            const float* w3r = &W3[t * 128];
#pragma unroll 8
            for (int j = 0; j < 128; ++j) s = fmaf(w3r[j], Tc[j], s);
            WcT[c * 256 + t] = s;
        } else {
            __shared__ float v[32];
            if (t < 32) {
                float s = b4[t];
                for (int j = 0; j < 128; ++j) s = fmaf(b3[j], W4[j * 32 + t], s);
                v[t] = s;
            }
            __syncthreads();
            if (t < 10) {
                float s = b5[t];
                for (int k = 0; k < 32; ++k) s = fmaf(v[k], W5[k * 10 + t], s);
                bc[t] = s;
            }
        }
        return;
    }
    if (b < 11 + nb) {
        int g = (b - 11) * 256 + t;
        if (g > G) return;
        int lo = 0, hi = N;
        while (lo < hi) { int mid = (lo + hi) >> 1; if (batch[mid] < g) lo = mid + 1; else hi = mid; }
        bounds[g] = lo;
        return;
    }
    int i = (b - 11 - nb) * 256 + t;
    if (i < n4) {
        float4 v = ((const float4*)x)[i];
        ushort4 o;
        o.x = f2b(v.x); o.y = f2b(v.y); o.z = f2b(v.z); o.w = f2b(v.w);
        ((ushort4*)xb)[i] = o;
        return;
    }
    i -= n4;
    if (i < K1 * N1) {
        int k = i / N1, n = i % N1;
        w1t[(size_t)n * K1 + k] = f2b(W1[i]);
        return;
    }
    i -= K1 * N1;
    if (i < K2 * N2) {
        int k = i / N2, n = i % N2;
        w2t[(size_t)n * K2 + k] = f2b(W2[i]);
    }
}

// gather-aggregate over packed dst-CSR, bf16 in/out, ILP-4 edge loop.
template <int F>
__global__ __launch_bounds__(256) void k_gather_b(const unsigned short* __restrict__ H,
        const int* __restrict__ row_off, const int2* __restrict__ csr,
        const float* __restrict__ dinv,
        const float* __restrict__ bias, unsigned short* __restrict__ outb, int N) {
    const int LPN = F / 8;
    const int NPB = 256 / LPN;
    int node = blockIdx.x * NPB + threadIdx.x / LPN;
    if (node >= N) return;
    int f = (threadIdx.x % LPN) * 8;
    const unsigned short* Hf = H + f;
    float sc = dinv[node]; sc *= sc;
    float a[8];
    cvt8(*(const uint4*)&Hf[(size_t)node * F], a);
#pragma unroll
    for (int j = 0; j < 8; ++j) a[j] *= sc;
    if (bias) {
#pragma unroll
        for (int j = 0; j < 8; ++j) a[j] += bias[f + j];
    }
    int e0 = row_off[node], e1 = row_off[node + 1];
    int e = e0;
    // 4 independent row fetches in flight (latency hiding)
    for (; e + 4 <= e1; e += 4) {
        int2 c0 = csr[e + 0], c1 = csr[e + 1], c2 = csr[e + 2], c3 = csr[e + 3];
        uint4 v0 = *(const uint4*)&Hf[(size_t)c0.x * F];
        uint4 v1 = *(const uint4*)&Hf[(size_t)c1.x * F];
        uint4 v2 = *(const uint4*)&Hf[(size_t)c2.x * F];
        uint4 v3 = *(const uint4*)&Hf[(size_t)c3.x * F];
        float w0 = __int_as_float(c0.y), w1 = __int_as_float(c1.y);
        float w2 = __int_as_float(c2.y), w3 = __int_as_float(c3.y);
        float b0[8], b1[8], b2[8], b3[8];
        cvt8(v0, b0); cvt8(v1, b1); cvt8(v2, b2); cvt8(v3, b3);
#pragma unroll
        for (int j = 0; j < 8; ++j) {
            a[j] = fmaf(w0, b0[j], a[j]);
            a[j] = fmaf(w1, b1[j], a[j]);
            a[j] = fmaf(w2, b2[j], a[j]);
            a[j] = fmaf(w3, b3[j], a[j]);
        }
    }
    for (; e < e1; ++e) {
        int2 c = csr[e];
        float w = __int_as_float(c.y);
        float b[8];
        cvt8(*(const uint4*)&Hf[(size_t)c.x * F], b);
#pragma unroll
        for (int j = 0; j < 8; ++j) a[j] = fmaf(w, b[j], a[j]);
    }
    uint4 o;
    o.x = (unsigned)f2b(a[0]) | ((unsigned)f2b(a[1]) << 16);
    o.y = (unsigned)f2b(a[2]) | ((unsigned)f2b(a[3]) << 16);
    o.z = (unsigned)f2b(a[4]) | ((unsigned)f2b(a[5]) << 16);
    o.w = (unsigned)f2b(a[6]) | ((unsigned)f2b(a[7]) << 16);
    *(uint4*)&outb[(size_t)node * F + f] = o;
}

// bf16 MFMA GEMM, fat-N tile: 128x256 per block, 512 threads = 8 waves (2x4),
// each wave 64x64 via 4x4 grid of 16x16x32 MFMAs, BK=64, global_load_lds w16,
// XOR-swizzled LDS, operand-swap mfma (lane = row + 4 contiguous cols).
template <int OUT_BF16, int ACT>
__global__ __launch_bounds__(512) void k_gemm_mfma256(const unsigned short* __restrict__ A,
        const unsigned short* __restrict__ Bt, const float* __restrict__ bias,
        void* __restrict__ Cout, int M, int K, int NC) {
    __shared__ __align__(16) unsigned short As[128][64];
    __shared__ __align__(16) unsigned short Bs[256][64];
    int tid = threadIdx.x;
    int wave = tid >> 6, lane = tid & 63;
    int row0 = blockIdx.y * 128, col0 = blockIdx.x * 256;
    int wr = (wave >> 2) * 64, wc = (wave & 3) * 64;
    f32x4 acc[4][4] = {};
    int lr = lane & 15;
    int lg = lane >> 4;
    int sw = ((lane & 7) ^ (lane >> 3)) << 3;
    int ch0 = (lg ^ (lr & 7)) << 3;
    int ch1 = ch0 ^ (4 << 3);

    for (int k0 = 0; k0 < K; k0 += 64) {
#pragma unroll
        for (int c = 0; c < 2; ++c) {
            int rl = c * 64 + wave * 8 + (lane >> 3);
            int gr = min(row0 + rl, M - 1);
            gl16(&As[c * 64 + wave * 8][0], &A[(size_t)gr * K + k0 + sw]);
        }
#pragma unroll
        for (int c = 0; c < 4; ++c) {
            int rl = c * 64 + wave * 8 + (lane >> 3);
            gl16(&Bs[c * 64 + wave * 8][0], &Bt[(size_t)(col0 + rl) * K + k0 + sw]);
        }
        __syncthreads();
        bf16x8 af[2][4], bv[2][4];
#pragma unroll
        for (int i = 0; i < 4; ++i) {
            int ra = wr + i * 16 + lr;
            int rb = wc + i * 16 + lr;
            af[0][i] = *(const bf16x8*)&As[ra][ch0];
            af[1][i] = *(const bf16x8*)&As[ra][ch1];
            bv[0][i] = *(const bf16x8*)&Bs[rb][ch0];
            bv[1][i] = *(const bf16x8*)&Bs[rb][ch1];
        }
#pragma unroll
        for (int s = 0; s < 2; ++s)
#pragma unroll
            for (int i = 0; i < 4; ++i)
#pragma unroll
                for (int j = 0; j < 4; ++j)
                    acc[i][j] = __builtin_amdgcn_mfma_f32_16x16x32_bf16(bv[s][j], af[s][i], acc[i][j], 0, 0, 0);
        __syncthreads();
    }

    int q4 = lg * 4;
    float4 bb[4];
#pragma unroll
    for (int j = 0; j < 4; ++j)
        bb[j] = bias ? *(const float4*)&bias[col0 + wc + j * 16 + q4]
                     : make_float4(0.f, 0.f, 0.f, 0.f);
#pragma unroll
    for (int i = 0; i < 4; ++i) {
        int row = row0 + wr + i * 16 + lr;
        if (row >= M) continue;
#pragma unroll
        for (int j = 0; j < 4; ++j) {
            int c0 = col0 + wc + j * 16 + q4;
            float4 v;
            v.x = acc[i][j][0] + bb[j].x;
            v.y = acc[i][j][1] + bb[j].y;
            v.z = acc[i][j][2] + bb[j].z;
            v.w = acc[i][j][3] + bb[j].w;
            if (ACT) {
                v.x = (v.x >= 0.f) ? v.x : 0.01f * v.x;
                v.y = (v.y >= 0.f) ? v.y : 0.01f * v.y;
                v.z = (v.z >= 0.f) ? v.z : 0.01f * v.z;
                v.w = (v.w >= 0.f) ? v.w : 0.01f * v.w;
            }
            if (OUT_BF16) {
                uint2 o;
                o.x = (unsigned)f2b(v.x) | ((unsigned)f2b(v.y) << 16);
                o.y = (unsigned)f2b(v.z) | ((unsigned)f2b(v.w) << 16);
                *(uint2*)&((unsigned short*)Cout)[(size_t)row * NC + c0] = o;
            } else {
                *(float4*)&((float*)Cout)[(size_t)row * NC + c0] = v;
            }
        }
    }
}

// fused per-graph output: phase A = head (h2 @ Wc + bc, max over rows -> out[g,:10]);
// phase B = feature-wise segment_max of h2 -> out_emb[g,:256].
__global__ __launch_bounds__(320) void k_head_segmax(const unsigned short* __restrict__ H,
        const float* __restrict__ WcT, const float* __restrict__ bc,
        const int* __restrict__ bounds, float* __restrict__ out,
        float* __restrict__ out_emb) {
    __shared__ __align__(16) float Ws[10][260];
    __shared__ float bs[10];
    __shared__ float red[320];
    int t = threadIdx.x;
    for (int i = t; i < 2560; i += 320) Ws[i / 256][i % 256] = WcT[i];
    if (t < 10) bs[t] = bc[t];
    __syncthreads();
    int g = blockIdx.x;
    int s = bounds[g], e = bounds[g + 1];
    int col = t % 10, rs = t / 10;
    float m = -INFINITY;
    for (int r = s + rs; r < e; r += 32) {
        const unsigned short* hr = &H[(size_t)r * 256];
        float acc = bs[col];
#pragma unroll 4
        for (int k = 0; k < 256; k += 8) {
            float h[8];
            cvt8(*(const uint4*)&hr[k], h);
            float4 wa = *(const float4*)&Ws[col][k];
            float4 wb = *(const float4*)&Ws[col][k + 4];
            acc = fmaf(h[0], wa.x, acc);
            acc = fmaf(h[1], wa.y, acc);
            acc = fmaf(h[2], wa.z, acc);
            acc = fmaf(h[3], wa.w, acc);
            acc = fmaf(h[4], wb.x, acc);
            acc = fmaf(h[5], wb.y, acc);
            acc = fmaf(h[6], wb.z, acc);
            acc = fmaf(h[7], wb.w, acc);
        }
        m = fmaxf(m, acc);
    }
    red[t] = m;
    __syncthreads();
    for (int step = 16; step >= 1; step >>= 1) {
        if (rs < step) red[rs * 10 + col] = fmaxf(red[rs * 10 + col], red[(rs + step) * 10 + col]);
        __syncthreads();
    }
    if (rs == 0) out[(size_t)g * 10 + col] = red[col];
    if (t < 256) {
        float mm = -INFINITY;
        for (int r = s; r < e; ++r)
            mm = fmaxf(mm, __uint_as_float(((unsigned)H[(size_t)r * 256 + t]) << 16));
        out_emb[(size_t)g * 256 + t] = mm;
    }
}

extern "C" void kernel_launch(void* const* d_in, const int* in_sizes, int n_in,
                              void* d_out, int out_size, void* d_ws, size_t ws_size,
                              hipStream_t stream) {
    const float* x  = (const float*)d_in[0];
    const int* ei   = (const int*)d_in[1];
    const int* batch= (const int*)d_in[2];
    const float* W1 = (const float*)d_in[3];
    const float* b1 = (const float*)d_in[4];
    const float* W2 = (const float*)d_in[5];
    const float* b2 = (const float*)d_in[6];
    const float* W3 = (const float*)d_in[7];
    const float* b3 = (const float*)d_in[8];
    const float* W4 = (const float*)d_in[9];
    const float* b4 = (const float*)d_in[10];
    const float* W5 = (const float*)d_in[11];
    const float* b5 = (const float*)d_in[12];

    const int N  = in_sizes[2];           // 50000
    const int F  = in_sizes[0] / N;       // 128
    const int E  = in_sizes[1] / 2;       // 400000
    const int C1 = in_sizes[4];           // 512
    const int C2 = in_sizes[6];           // 256
    const int C5 = in_sizes[12];          // 10
    const int G  = out_size / (C2 + C5);  // 512
    const int NB = DIV_UP(N, 1024);

    const int* srcp = ei;
    const int* dstp = ei + E;

    // ---- workspace layout (256B-aligned carve-outs) ----
    uintptr_t p = (uintptr_t)d_ws;
    auto carve = [&](size_t bytes) {
        uintptr_t r = p;
        p += (bytes + 255) & ~(size_t)255;
        return (void*)r;
    };
    int* hist    = (int*)carve(sizeof(int) * N);
    int* cursor  = (int*)carve(sizeof(int) * N);      // MUST follow hist (joint memset)
    int* row_off = (int*)carve(sizeof(int) * (N + 1));
    int* bounds  = (int*)carve(sizeof(int) * (G + 1));
    int* bsum    = (int*)carve(sizeof(int) * NB);
    int* boff    = (int*)carve(sizeof(int) * NB);
    int2* csr    = (int2*)carve(sizeof(int2) * E);
    float* dinv  = (float*)carve(sizeof(float) * N);
    float* wct   = (float*)carve(sizeof(float) * C2 * C5);
    float* bcv   = (float*)carve(sizeof(float) * C5);
    unsigned short* w1t = (unsigned short*)carve(sizeof(short) * F * C1);
    unsigned short* w2t = (unsigned short*)carve(sizeof(short) * C1 * C2);
    unsigned short* xb    = (unsigned short*)carve(sizeof(short) * (size_t)N * F);
    unsigned short* aggxb = (unsigned short*)carve(sizeof(short) * (size_t)N * F);
    unsigned short* h1b   = (unsigned short*)carve(sizeof(short) * (size_t)N * C1);
    unsigned short* t2b   = (unsigned short*)carve(sizeof(short) * (size_t)N * C2);
    unsigned short* h2b   = (unsigned short*)carve(sizeof(short) * (size_t)N * C2);

    float* out     = (float*)d_out;
    float* out_emb = out + (size_t)G * C5;

    // ---- CSR build + fused preprocessing ----
    size_t zbytes = (uintptr_t)(cursor + N) - (uintptr_t)hist;   // hist..cursor contiguous
    hipMemsetAsync(hist, 0, zbytes, stream);
    k_hist<<<DIV_UP(E, 256), 256, 0, stream>>>(dstp, hist, E);
    k_scan_bsum<<<NB, 256, 0, stream>>>(hist, bsum, N);
    k_scan_boff<<<1, 1024, 0, stream>>>(bsum, boff, row_off, NB, N);
    k_scan_apply<<<NB, 256, 0, stream>>>(hist, boff, row_off, dinv, N);
    k_bin<<<DIV_UP(E, 256), 256, 0, stream>>>(srcp, dstp, row_off, cursor, dinv, csr, E);

    int n4 = N * F / 4;
    int nb_bounds = DIV_UP(G + 1, 256);
    int prep_total = n4 + F * C1 + C1 * C2;
    int pre_blocks = 11 + nb_bounds + DIV_UP(prep_total, 256);
    k_pre<<<pre_blocks, 256, 0, stream>>>(W3, W4, W5, b3, b4, b5, wct, bcv,
                                          batch, bounds, N, G, nb_bounds,
                                          x, xb, n4, W1, w1t, F, C1, W2, w2t, C1, C2);

    // ---- layer 1: gather (bf16) -> fat-N MFMA GEMM + bias + leakyrelu -> h1 bf16 ----
    k_gather_b<128><<<DIV_UP(N, 16), 256, 0, stream>>>(
        xb, row_off, csr, dinv, nullptr, aggxb, N);
    dim3 g1(C1 / 256, DIV_UP(N, 128));
    k_gemm_mfma256<1, 1><<<g1, 512, 0, stream>>>(aggxb, w1t, b1, h1b, N, F, C1);

    // ---- layer 2: fat-N MFMA GEMM -> t2 bf16 -> gather (+b2) -> h2 bf16 ----
    dim3 g2(C2 / 256, DIV_UP(N, 128));
    k_gemm_mfma256<1, 0><<<g2, 512, 0, stream>>>(h1b, w2t, nullptr, t2b, N, C1, C2);
    k_gather_b<256><<<DIV_UP(N, 8), 256, 0, stream>>>(
        t2b, row_off, csr, dinv, b2, h2b, N);

    // ---- fused head + both segment_maxes ----
    k_head_segmax<<<G, 320, 0, stream>>>(h2b, wct, bcv, bounds, out, out_emb);
}